// Round 3
// baseline (1335.686 us; speedup 1.0000x reference)
//
#include <hip/hip_runtime.h>
#include <math.h>

// ---------------------------------------------------------------------------
// GCN: 3x (GEMM(+dis scale) -> pull-aggregate (+self loop, bias, tanh))
//      -> mean pool -> head -> log_softmax
// R3: bucketed CSR build (64 dst-nodes per bucket) to kill the 16x write
//     amplification of random 4B scatters; aggregate uses float4 half-wave
//     gathers (32 lanes x 16B, 2 edge streams per wave).
// ---------------------------------------------------------------------------

// ---- phase A: histogram edges into dst-buckets (bucket = dst >> 6) --------
__global__ void bucket_hist(const int* __restrict__ dst, int* __restrict__ bcnt, int E) {
    int e = blockIdx.x * 256 + threadIdx.x;
    if (e < E) atomicAdd(&bcnt[dst[e] >> 6], 1);
}

// ---- 3-kernel exclusive scan (n <= 65536, 256/block) ----------------------
__global__ void scan_block(const int* __restrict__ cnt, int* __restrict__ off,
                           int* __restrict__ bsum, int n) {
    __shared__ int lds[256];
    int t = threadIdx.x;
    int i = blockIdx.x * 256 + t;
    int v = (i < n) ? cnt[i] : 0;
    lds[t] = v;
    __syncthreads();
    for (int d = 1; d < 256; d <<= 1) {
        int add = (t >= d) ? lds[t - d] : 0;
        __syncthreads();
        lds[t] += add;
        __syncthreads();
    }
    if (i < n) off[i] = lds[t] - v;
    if (t == 255) bsum[blockIdx.x] = lds[255];
}

__global__ void scan_top(const int* __restrict__ bsum, int* __restrict__ boff,
                         int* __restrict__ off, int nblocks, int n) {
    __shared__ int lds[256];
    int t = threadIdx.x;
    int v = (t < nblocks) ? bsum[t] : 0;
    lds[t] = v;
    __syncthreads();
    for (int d = 1; d < 256; d <<= 1) {
        int add = (t >= d) ? lds[t - d] : 0;
        __syncthreads();
        lds[t] += add;
        __syncthreads();
    }
    if (t < nblocks) boff[t] = lds[t] - v;
    if (t == 255) off[n] = lds[255];
}

__global__ void scan_add(int* __restrict__ off, const int* __restrict__ boff, int n) {
    int i = blockIdx.x * 256 + threadIdx.x;
    if (i < n) off[i] += boff[blockIdx.x];
}

// ---- phase C: scatter packed (dstLocal, src) into bucket regions ----------
__global__ void scatter_pairs(const int* __restrict__ src, const int* __restrict__ dst,
                              const int* __restrict__ boffE, int* __restrict__ bcur,
                              unsigned* __restrict__ packed, int E) {
    int e = blockIdx.x * 256 + threadIdx.x;
    if (e >= E) return;
    int d = dst[e];
    int b = d >> 6;
    int p = boffE[b] + atomicAdd(&bcur[b], 1);
    packed[p] = ((unsigned)(d & 63) << 26) | (unsigned)src[e];
}

// ---- phase D: per-bucket node counts via LDS, fused dis = rsqrt(cnt+1) ----
__global__ __launch_bounds__(256) void bucket_cnt(const unsigned* __restrict__ packed,
        const int* __restrict__ boffE, int* __restrict__ cnt,
        float* __restrict__ dis, int N) {
    __shared__ int c64[64];
    int b = blockIdx.x;
    int t = threadIdx.x;
    if (t < 64) c64[t] = 0;
    __syncthreads();
    int lo = boffE[b], hi = boffE[b + 1];
    for (int i = lo + t; i < hi; i += 256)
        atomicAdd(&c64[packed[i] >> 26], 1);
    __syncthreads();
    if (t < 64) {
        int node = b * 64 + t;
        if (node < N) {
            int c = c64[t];
            cnt[node] = c;
            dis[node] = rsqrtf((float)c + 1.0f);
        }
    }
}

// ---- phase E: per-bucket CSR fill (writes land in ~8KB contiguous window) -
__global__ __launch_bounds__(256) void bucket_fill(const unsigned* __restrict__ packed,
        const int* __restrict__ boffE, const int* __restrict__ off,
        int* __restrict__ csr_src, int N) {
    __shared__ int offL[64];
    __shared__ int cur[64];
    int b = blockIdx.x;
    int t = threadIdx.x;
    if (t < 64) {
        int node = b * 64 + t;
        offL[t] = (node < N) ? off[node] : 0;
        cur[t] = 0;
    }
    __syncthreads();
    int lo = boffE[b], hi = boffE[b + 1];
    for (int i = lo + t; i < hi; i += 256) {
        unsigned p = packed[i];
        int l = p >> 26;
        int s = (int)(p & 0x03FFFFFFu);
        int pos = atomicAdd(&cur[l], 1);
        csr_src[offL[l] + pos] = s;
    }
}

// ---- GEMM: Hs[r] = dis[r] * (A[r] @ W),  A: n x 128, W: 128 x 128 ---------
__global__ __launch_bounds__(256, 2) void gemm128v2(const float* __restrict__ A,
        const float* __restrict__ W, const float* __restrict__ dis,
        float* __restrict__ Hs, int n) {
    __shared__ float As[64 * 128];   // As[k*128 + r]
    __shared__ float Ws[64 * 128];   // Ws[k*128 + c]
    int t = threadIdx.x;
    int row0 = blockIdx.x * 128;
    int rg = (t & 15) * 8;
    int cg = (t >> 4) * 8;

    float acc[8][8];
#pragma unroll
    for (int i = 0; i < 8; ++i)
#pragma unroll
        for (int j = 0; j < 8; ++j) acc[i][j] = 0.f;

    for (int kk = 0; kk < 128; kk += 64) {
        __syncthreads();
        {
            int r = t & 127;
            int q = t >> 7;
            int grow = row0 + r;
            const float* Ap = A + (size_t)grow * 128 + kk + q * 32;
#pragma unroll
            for (int j = 0; j < 8; ++j) {
                float4 f;
                if (grow < n) f = ((const float4*)Ap)[j];
                else          f = float4{0.f, 0.f, 0.f, 0.f};
                int kb = q * 32 + j * 4;
                As[(kb + 0) * 128 + r] = f.x;
                As[(kb + 1) * 128 + r] = f.y;
                As[(kb + 2) * 128 + r] = f.z;
                As[(kb + 3) * 128 + r] = f.w;
            }
        }
        {
            const float4* Wp = (const float4*)(W + (size_t)kk * 128);
            float4* Wl = (float4*)Ws;
            for (int i = t; i < 64 * 128 / 4; i += 256) Wl[i] = Wp[i];
        }
        __syncthreads();
#pragma unroll 4
        for (int k = 0; k < 64; ++k) {
            float4 a0 = *(const float4*)&As[k * 128 + rg];
            float4 a1 = *(const float4*)&As[k * 128 + rg + 4];
            float4 w0 = *(const float4*)&Ws[k * 128 + cg];
            float4 w1 = *(const float4*)&Ws[k * 128 + cg + 4];
            float a[8] = {a0.x, a0.y, a0.z, a0.w, a1.x, a1.y, a1.z, a1.w};
            float w[8] = {w0.x, w0.y, w0.z, w0.w, w1.x, w1.y, w1.z, w1.w};
#pragma unroll
            for (int i = 0; i < 8; ++i)
#pragma unroll
                for (int j = 0; j < 8; ++j)
                    acc[i][j] = fmaf(a[i], w[j], acc[i][j]);
        }
    }
#pragma unroll
    for (int i = 0; i < 8; ++i) {
        int r = row0 + rg + i;
        if (r < n) {
            float d = dis[r];
            float4 o0 = {acc[i][0] * d, acc[i][1] * d, acc[i][2] * d, acc[i][3] * d};
            float4 o1 = {acc[i][4] * d, acc[i][5] * d, acc[i][6] * d, acc[i][7] * d};
            float* Op = Hs + (size_t)r * 128 + cg;
            *(float4*)Op = o0;
            *(float4*)(Op + 4) = o1;
        }
    }
}

// ---- pull aggregation: float4 half-wave gathers, 16 edges per wave-iter ---
__global__ __launch_bounds__(256) void aggregate(const float* __restrict__ hs,
    const int* __restrict__ csr_src, const int* __restrict__ off,
    const float* __restrict__ dis, const float* __restrict__ bias,
    float* __restrict__ out, int n, int do_tanh) {
    int node = blockIdx.x * 4 + (threadIdx.x >> 6);
    if (node >= n) return;
    int lane = threadIdx.x & 63;
    int half = lane >> 5;          // edge stream 0/1
    int fq = lane & 31;            // feature quad 0..31 (covers 128 feats)
    const float4* H = (const float4*)hs;   // 32 float4 per row

    int e0 = off[node];
    int e1 = off[node + 1];
    int m = e1 - e0;
    int full = m & ~15;
    float4 a0 = {0.f, 0.f, 0.f, 0.f};
    float4 a1 = {0.f, 0.f, 0.f, 0.f};
    for (int i = 0; i < full; i += 16) {
        int base = e0 + i + half;
        int s[8];
#pragma unroll
        for (int j = 0; j < 8; ++j) s[j] = csr_src[base + 2 * j];
        float4 v[8];
#pragma unroll
        for (int j = 0; j < 8; ++j) v[j] = H[(size_t)s[j] * 32 + fq];
#pragma unroll
        for (int j = 0; j < 8; j += 2) {
            a0.x += v[j].x;     a0.y += v[j].y;     a0.z += v[j].z;     a0.w += v[j].w;
            a1.x += v[j + 1].x; a1.y += v[j + 1].y; a1.z += v[j + 1].z; a1.w += v[j + 1].w;
        }
    }
    for (int e = e0 + full + half; e < e1; e += 2) {
        int s = csr_src[e];
        float4 v = H[(size_t)s * 32 + fq];
        a0.x += v.x; a0.y += v.y; a0.z += v.z; a0.w += v.w;
    }
    float4 acc = {a0.x + a1.x, a0.y + a1.y, a0.z + a1.z, a0.w + a1.w};
    // combine the two half-wave edge streams (lane l and l+32 share fq)
    acc.x += __shfl_xor(acc.x, 32, 64);
    acc.y += __shfl_xor(acc.y, 32, 64);
    acc.z += __shfl_xor(acc.z, 32, 64);
    acc.w += __shfl_xor(acc.w, 32, 64);

    float4 hv = H[(size_t)node * 32 + fq];   // self loop (row pre-scaled by dn)
    float dn = dis[node];
    float4 bv = ((const float4*)bias)[fq];
    float4 o;
    o.x = fmaf(dn, acc.x + hv.x, bv.x);
    o.y = fmaf(dn, acc.y + hv.y, bv.y);
    o.z = fmaf(dn, acc.z + hv.z, bv.z);
    o.w = fmaf(dn, acc.w + hv.w, bv.w);
    if (do_tanh) {
        o.x = tanhf(o.x); o.y = tanhf(o.y); o.z = tanhf(o.z); o.w = tanhf(o.w);
    }
    if (half == 0)
        *(float4*)(out + (size_t)node * 128 + fq * 4) = o;
}

// ---- per-graph node ranges via binary search on sorted batch --------------
__global__ void graph_starts(const int* __restrict__ batch, int* __restrict__ gstart,
                             int n, int G) {
    int g = blockIdx.x * 64 + threadIdx.x;
    if (g > G) return;
    int lo = 0, hi = n;
    while (lo < hi) {
        int mid = (lo + hi) >> 1;
        if (batch[mid] < g) lo = mid + 1; else hi = mid;
    }
    gstart[g] = lo;
}

__global__ __launch_bounds__(64) void pool_mean(const float* __restrict__ act,
    const int* __restrict__ gstart, float* __restrict__ pooled, int G) {
    int g = blockIdx.x;
    int l = threadIdx.x;
    int lo = gstart[g], hi = gstart[g + 1];
    float accx = 0.f, accy = 0.f;
    for (int i = lo; i < hi; ++i) {
        const float2 v = *(const float2*)(act + (size_t)i * 128 + l * 2);
        accx += v.x;
        accy += v.y;
    }
    int cnt = hi - lo;
    float inv = 1.0f / (float)(cnt > 0 ? cnt : 1);
    pooled[(size_t)g * 128 + 2 * l]     = accx * inv;
    pooled[(size_t)g * 128 + 2 * l + 1] = accy * inv;
}

__global__ __launch_bounds__(64) void head_kernel(const float* __restrict__ pooled,
    const float* __restrict__ Wout, const float* __restrict__ bout,
    float* __restrict__ out, int C) {
    __shared__ float l[16];
    __shared__ float stats[2];
    int g = blockIdx.x;
    int t = threadIdx.x;
    if (t < C) {
        float acc = bout[t];
        for (int f = 0; f < 128; ++f)
            acc = fmaf(pooled[(size_t)g * 128 + f], Wout[(size_t)f * C + t], acc);
        l[t] = acc;
    }
    __syncthreads();
    if (t == 0) {
        float m = -1e30f;
        for (int c = 0; c < C; ++c) m = fmaxf(m, l[c]);
        float s = 0.f;
        for (int c = 0; c < C; ++c) s += expf(l[c] - m);
        stats[0] = m;
        stats[1] = logf(s);
    }
    __syncthreads();
    if (t < C) out[(size_t)g * C + t] = l[t] - stats[0] - stats[1];
}

// ---------------------------------------------------------------------------
extern "C" void kernel_launch(void* const* d_in, const int* in_sizes, int n_in,
                              void* d_out, int out_size, void* d_ws, size_t ws_size,
                              hipStream_t stream) {
    const float* x     = (const float*)d_in[0];
    const int*   edge  = (const int*)d_in[1];
    const int*   batch = (const int*)d_in[2];
    const float* W0 = (const float*)d_in[3];
    const float* b0 = (const float*)d_in[4];
    const float* W1 = (const float*)d_in[5];
    const float* b1 = (const float*)d_in[6];
    const float* W2 = (const float*)d_in[7];
    const float* b2 = (const float*)d_in[8];
    const float* Wout = (const float*)d_in[9];
    const float* bout = (const float*)d_in[10];
    float* out = (float*)d_out;

    const int N = in_sizes[0] / 128;   // 50000
    const int E = in_sizes[1] / 2;     // 1600000
    const int C = in_sizes[10];        // 10
    const int G = out_size / C;        // 512

    const int* src = edge;
    const int* dst = edge + E;

    const int NB = (N + 63) / 64;      // buckets of 64 dst nodes (782)

    char* p = (char*)d_ws;
    auto alloc = [&](size_t bytes) -> void* {
        void* r = (void*)p;
        p += (bytes + 255) & ~(size_t)255;
        return r;
    };
    float*    h       = (float*)alloc((size_t)N * 128 * 4);
    float*    act     = (float*)alloc((size_t)N * 128 * 4);
    float*    dis     = (float*)alloc((size_t)N * 4);
    int*      cnt     = (int*)alloc((size_t)N * 4);
    int*      off     = (int*)alloc((size_t)(N + 1) * 4);
    int*      bcnt    = (int*)alloc((size_t)NB * 4);
    int*      bcur    = (int*)alloc((size_t)NB * 4);
    int*      boffE   = (int*)alloc((size_t)(NB + 1) * 4);
    int*      bsum    = (int*)alloc(256 * 4);
    int*      boff    = (int*)alloc(256 * 4);
    unsigned* packed  = (unsigned*)alloc((size_t)E * 4);
    int*      csr_src = (int*)alloc((size_t)E * 4);
    int*      gstart  = (int*)alloc((size_t)(G + 1) * 4);
    float*    pooled  = (float*)alloc((size_t)G * 128 * 4);

    hipMemsetAsync(bcnt, 0, (size_t)NB * 4, stream);
    hipMemsetAsync(bcur, 0, (size_t)NB * 4, stream);

    const int eb  = (E + 255) / 256;
    const int nb  = (N + 255) / 256;    // node-scan blocks (196)
    const int nbb = (NB + 255) / 256;   // bucket-scan blocks (4)

    // CSR build
    bucket_hist<<<eb, 256, 0, stream>>>(dst, bcnt, E);
    scan_block<<<nbb, 256, 0, stream>>>(bcnt, boffE, bsum, NB);
    scan_top<<<1, 256, 0, stream>>>(bsum, boff, boffE, nbb, NB);
    scan_add<<<nbb, 256, 0, stream>>>(boffE, boff, NB);
    scatter_pairs<<<eb, 256, 0, stream>>>(src, dst, boffE, bcur, packed, E);
    bucket_cnt<<<NB, 256, 0, stream>>>(packed, boffE, cnt, dis, N);
    scan_block<<<nb, 256, 0, stream>>>(cnt, off, bsum, N);
    scan_top<<<1, 256, 0, stream>>>(bsum, boff, off, nb, N);
    scan_add<<<nb, 256, 0, stream>>>(off, boff, N);
    bucket_fill<<<NB, 256, 0, stream>>>(packed, boffE, off, csr_src, N);

    const int gb = (N + 127) / 128;
    const int ab = (N + 3) / 4;

    gemm128v2<<<gb, 256, 0, stream>>>(x,   W0, dis, h, N);
    aggregate<<<ab, 256, 0, stream>>>(h, csr_src, off, dis, b0, act, N, 1);
    gemm128v2<<<gb, 256, 0, stream>>>(act, W1, dis, h, N);
    aggregate<<<ab, 256, 0, stream>>>(h, csr_src, off, dis, b1, act, N, 1);
    gemm128v2<<<gb, 256, 0, stream>>>(act, W2, dis, h, N);
    aggregate<<<ab, 256, 0, stream>>>(h, csr_src, off, dis, b2, act, N, 0);

    graph_starts<<<(G + 64) / 64, 64, 0, stream>>>(batch, gstart, N, G);
    pool_mean<<<G, 64, 0, stream>>>(act, gstart, pooled, G);
    head_kernel<<<G, 64, 0, stream>>>(pooled, Wout, bout, out, C);
}

// Round 4
// 580.138 us; speedup vs baseline: 2.3024x; 2.3024x over previous
//
#include <hip/hip_runtime.h>
#include <math.h>

// ---------------------------------------------------------------------------
// GCN: 3x (GEMM(+dis scale, bf16 out) -> pull-aggregate -> bias -> tanh)
//      -> mean pool -> head -> log_softmax
// R4: revert CSR build to R2 scheme (per-node cursors: contention beats the
//     R3 bucket-cursor serialization). Gather table hs is bf16 (halves
//     aggregate fetch traffic). Aggregate: half-wave gathers, 2 edge streams,
//     16-edge batches; bf16 unpack via shift/and (no cvt).
// ---------------------------------------------------------------------------

static __device__ inline unsigned short f2bf(float f) {
    unsigned u = __float_as_uint(f);
    unsigned r = (u + 0x7FFFu + ((u >> 16) & 1u)) >> 16;   // RNE
    return (unsigned short)r;
}

// ---- degree histogram over dst --------------------------------------------
__global__ void hist_dst(const int* __restrict__ dst, int* __restrict__ cnt, int E) {
    int e = blockIdx.x * 256 + threadIdx.x;
    if (e < E) atomicAdd(&cnt[dst[e]], 1);
}

__global__ void calc_dis(const int* __restrict__ cnt, float* __restrict__ dis, int n) {
    int i = blockIdx.x * 256 + threadIdx.x;
    if (i < n) dis[i] = rsqrtf((float)cnt[i] + 1.0f);
}

// ---- 3-kernel exclusive scan of cnt -> off (nblocks must be <= 256) -------
__global__ void scan_block(const int* __restrict__ cnt, int* __restrict__ off,
                           int* __restrict__ bsum, int n) {
    __shared__ int lds[256];
    int t = threadIdx.x;
    int i = blockIdx.x * 256 + t;
    int v = (i < n) ? cnt[i] : 0;
    lds[t] = v;
    __syncthreads();
    for (int d = 1; d < 256; d <<= 1) {
        int add = (t >= d) ? lds[t - d] : 0;
        __syncthreads();
        lds[t] += add;
        __syncthreads();
    }
    if (i < n) off[i] = lds[t] - v;
    if (t == 255) bsum[blockIdx.x] = lds[255];
}

__global__ void scan_top(const int* __restrict__ bsum, int* __restrict__ boff,
                         int* __restrict__ off, int nblocks, int n) {
    __shared__ int lds[256];
    int t = threadIdx.x;
    int v = (t < nblocks) ? bsum[t] : 0;
    lds[t] = v;
    __syncthreads();
    for (int d = 1; d < 256; d <<= 1) {
        int add = (t >= d) ? lds[t - d] : 0;
        __syncthreads();
        lds[t] += add;
        __syncthreads();
    }
    if (t < nblocks) boff[t] = lds[t] - v;
    if (t == 255) off[n] = lds[255];
}

__global__ void scan_add(int* __restrict__ off, const int* __restrict__ boff, int n) {
    int i = blockIdx.x * 256 + threadIdx.x;
    if (i < n) off[i] += boff[blockIdx.x];
}

// ---- scatter edges into CSR slots (per-node atomic cursor, R2 scheme) -----
__global__ void fill_csr(const int* __restrict__ src, const int* __restrict__ dst,
                         const int* __restrict__ off, int* __restrict__ cursor,
                         int* __restrict__ csr_src, int E) {
    int e = blockIdx.x * 256 + threadIdx.x;
    if (e >= E) return;
    int d = dst[e];
    int p = off[d] + atomicAdd(&cursor[d], 1);
    __builtin_nontemporal_store(src[e], &csr_src[p]);
}

// ---- GEMM: Hs16[r] = bf16( dis[r] * (A[r] @ W) ),  A: n x 128 -------------
__global__ __launch_bounds__(256, 2) void gemm128v2(const float* __restrict__ A,
        const float* __restrict__ W, const float* __restrict__ dis,
        unsigned short* __restrict__ Hs16, int n) {
    __shared__ float As[64 * 128];   // As[k*128 + r]
    __shared__ float Ws[64 * 128];   // Ws[k*128 + c]
    int t = threadIdx.x;
    int row0 = blockIdx.x * 128;
    int rg = (t & 15) * 8;
    int cg = (t >> 4) * 8;

    float acc[8][8];
#pragma unroll
    for (int i = 0; i < 8; ++i)
#pragma unroll
        for (int j = 0; j < 8; ++j) acc[i][j] = 0.f;

    for (int kk = 0; kk < 128; kk += 64) {
        __syncthreads();
        {
            int r = t & 127;
            int q = t >> 7;
            int grow = row0 + r;
            const float* Ap = A + (size_t)grow * 128 + kk + q * 32;
#pragma unroll
            for (int j = 0; j < 8; ++j) {
                float4 f;
                if (grow < n) f = ((const float4*)Ap)[j];
                else          f = float4{0.f, 0.f, 0.f, 0.f};
                int kb = q * 32 + j * 4;
                As[(kb + 0) * 128 + r] = f.x;
                As[(kb + 1) * 128 + r] = f.y;
                As[(kb + 2) * 128 + r] = f.z;
                As[(kb + 3) * 128 + r] = f.w;
            }
        }
        {
            const float4* Wp = (const float4*)(W + (size_t)kk * 128);
            float4* Wl = (float4*)Ws;
            for (int i = t; i < 64 * 128 / 4; i += 256) Wl[i] = Wp[i];
        }
        __syncthreads();
#pragma unroll 4
        for (int k = 0; k < 64; ++k) {
            float4 a0 = *(const float4*)&As[k * 128 + rg];
            float4 a1 = *(const float4*)&As[k * 128 + rg + 4];
            float4 w0 = *(const float4*)&Ws[k * 128 + cg];
            float4 w1 = *(const float4*)&Ws[k * 128 + cg + 4];
            float a[8] = {a0.x, a0.y, a0.z, a0.w, a1.x, a1.y, a1.z, a1.w};
            float w[8] = {w0.x, w0.y, w0.z, w0.w, w1.x, w1.y, w1.z, w1.w};
#pragma unroll
            for (int i = 0; i < 8; ++i)
#pragma unroll
                for (int j = 0; j < 8; ++j)
                    acc[i][j] = fmaf(a[i], w[j], acc[i][j]);
        }
    }
#pragma unroll
    for (int i = 0; i < 8; ++i) {
        int r = row0 + rg + i;
        if (r < n) {
            float d = dis[r];
            unsigned u0 = (unsigned)f2bf(acc[i][0] * d) | ((unsigned)f2bf(acc[i][1] * d) << 16);
            unsigned u1 = (unsigned)f2bf(acc[i][2] * d) | ((unsigned)f2bf(acc[i][3] * d) << 16);
            unsigned u2 = (unsigned)f2bf(acc[i][4] * d) | ((unsigned)f2bf(acc[i][5] * d) << 16);
            unsigned u3 = (unsigned)f2bf(acc[i][6] * d) | ((unsigned)f2bf(acc[i][7] * d) << 16);
            uint4 o = {u0, u1, u2, u3};
            *(uint4*)(Hs16 + (size_t)r * 128 + cg) = o;
        }
    }
}

// ---- pull aggregation over bf16 table -------------------------------------
// One wave per node; 2 edge streams (half-waves); 32 lanes x uint2 (4 bf16)
// covers one 256B row. out = tanh?( dn*(sum + self) + bias ), fp32.
__global__ __launch_bounds__(256) void aggregate(const unsigned short* __restrict__ hs,
    const int* __restrict__ csr_src, const int* __restrict__ off,
    const float* __restrict__ dis, const float* __restrict__ bias,
    float* __restrict__ out, int n, int do_tanh) {
    int node = blockIdx.x * 4 + (threadIdx.x >> 6);
    if (node >= n) return;
    int lane = threadIdx.x & 63;
    int half = lane >> 5;          // edge stream 0/1
    int fq = lane & 31;            // covers features [4*fq, 4*fq+4)
    const uint2* H = (const uint2*)hs;    // 32 uint2 per row

    int e0 = off[node];
    int e1 = off[node + 1];
    int m = e1 - e0;
    int full = m & ~15;
    float ax = 0.f, ay = 0.f, az = 0.f, aw = 0.f;
    for (int i = 0; i < full; i += 16) {
        int base = e0 + i + half;
        int s[8];
#pragma unroll
        for (int j = 0; j < 8; ++j) s[j] = csr_src[base + 2 * j];
        uint2 v[8];
#pragma unroll
        for (int j = 0; j < 8; ++j) v[j] = H[(size_t)s[j] * 32 + fq];
#pragma unroll
        for (int j = 0; j < 8; ++j) {
            ax += __uint_as_float(v[j].x << 16);
            ay += __uint_as_float(v[j].x & 0xFFFF0000u);
            az += __uint_as_float(v[j].y << 16);
            aw += __uint_as_float(v[j].y & 0xFFFF0000u);
        }
    }
    for (int e = e0 + full + half; e < e1; e += 2) {
        int s = csr_src[e];
        uint2 v = H[(size_t)s * 32 + fq];
        ax += __uint_as_float(v.x << 16);
        ay += __uint_as_float(v.x & 0xFFFF0000u);
        az += __uint_as_float(v.y << 16);
        aw += __uint_as_float(v.y & 0xFFFF0000u);
    }
    // combine the two half-wave edge streams (lane l and l^32 share fq)
    ax += __shfl_xor(ax, 32, 64);
    ay += __shfl_xor(ay, 32, 64);
    az += __shfl_xor(az, 32, 64);
    aw += __shfl_xor(aw, 32, 64);

    uint2 sv = H[(size_t)node * 32 + fq];   // self loop (row pre-scaled by dn)
    ax += __uint_as_float(sv.x << 16);
    ay += __uint_as_float(sv.x & 0xFFFF0000u);
    az += __uint_as_float(sv.y << 16);
    aw += __uint_as_float(sv.y & 0xFFFF0000u);

    float dn = dis[node];
    float4 bv = ((const float4*)bias)[fq];
    float4 o;
    o.x = fmaf(dn, ax, bv.x);
    o.y = fmaf(dn, ay, bv.y);
    o.z = fmaf(dn, az, bv.z);
    o.w = fmaf(dn, aw, bv.w);
    if (do_tanh) {
        o.x = tanhf(o.x); o.y = tanhf(o.y); o.z = tanhf(o.z); o.w = tanhf(o.w);
    }
    if (half == 0)
        *(float4*)(out + (size_t)node * 128 + fq * 4) = o;
}

// ---- per-graph node ranges via binary search on sorted batch --------------
__global__ void graph_starts(const int* __restrict__ batch, int* __restrict__ gstart,
                             int n, int G) {
    int g = blockIdx.x * 64 + threadIdx.x;
    if (g > G) return;
    int lo = 0, hi = n;
    while (lo < hi) {
        int mid = (lo + hi) >> 1;
        if (batch[mid] < g) lo = mid + 1; else hi = mid;
    }
    gstart[g] = lo;
}

__global__ __launch_bounds__(64) void pool_mean(const float* __restrict__ act,
    const int* __restrict__ gstart, float* __restrict__ pooled, int G) {
    int g = blockIdx.x;
    int l = threadIdx.x;
    int lo = gstart[g], hi = gstart[g + 1];
    float accx = 0.f, accy = 0.f;
    for (int i = lo; i < hi; ++i) {
        const float2 v = *(const float2*)(act + (size_t)i * 128 + l * 2);
        accx += v.x;
        accy += v.y;
    }
    int cnt = hi - lo;
    float inv = 1.0f / (float)(cnt > 0 ? cnt : 1);
    pooled[(size_t)g * 128 + 2 * l]     = accx * inv;
    pooled[(size_t)g * 128 + 2 * l + 1] = accy * inv;
}

__global__ __launch_bounds__(64) void head_kernel(const float* __restrict__ pooled,
    const float* __restrict__ Wout, const float* __restrict__ bout,
    float* __restrict__ out, int C) {
    __shared__ float l[16];
    __shared__ float stats[2];
    int g = blockIdx.x;
    int t = threadIdx.x;
    if (t < C) {
        float acc = bout[t];
        for (int f = 0; f < 128; ++f)
            acc = fmaf(pooled[(size_t)g * 128 + f], Wout[(size_t)f * C + t], acc);
        l[t] = acc;
    }
    __syncthreads();
    if (t == 0) {
        float m = -1e30f;
        for (int c = 0; c < C; ++c) m = fmaxf(m, l[c]);
        float s = 0.f;
        for (int c = 0; c < C; ++c) s += expf(l[c] - m);
        stats[0] = m;
        stats[1] = logf(s);
    }
    __syncthreads();
    if (t < C) out[(size_t)g * C + t] = l[t] - stats[0] - stats[1];
}

// ---------------------------------------------------------------------------
extern "C" void kernel_launch(void* const* d_in, const int* in_sizes, int n_in,
                              void* d_out, int out_size, void* d_ws, size_t ws_size,
                              hipStream_t stream) {
    const float* x     = (const float*)d_in[0];
    const int*   edge  = (const int*)d_in[1];
    const int*   batch = (const int*)d_in[2];
    const float* W0 = (const float*)d_in[3];
    const float* b0 = (const float*)d_in[4];
    const float* W1 = (const float*)d_in[5];
    const float* b1 = (const float*)d_in[6];
    const float* W2 = (const float*)d_in[7];
    const float* b2 = (const float*)d_in[8];
    const float* Wout = (const float*)d_in[9];
    const float* bout = (const float*)d_in[10];
    float* out = (float*)d_out;

    const int N = in_sizes[0] / 128;   // 50000
    const int E = in_sizes[1] / 2;     // 1600000
    const int C = in_sizes[10];        // 10
    const int G = out_size / C;        // 512

    const int* src = edge;
    const int* dst = edge + E;

    char* p = (char*)d_ws;
    auto alloc = [&](size_t bytes) -> void* {
        void* r = (void*)p;
        p += (bytes + 255) & ~(size_t)255;
        return r;
    };
    unsigned short* hs = (unsigned short*)alloc((size_t)N * 128 * 2);  // bf16 table
    float* act    = (float*)alloc((size_t)N * 128 * 4);
    float* dis    = (float*)alloc((size_t)N * 4);
    int*   cnt    = (int*)alloc((size_t)N * 4);
    int*   cursor = (int*)alloc((size_t)N * 4);
    int*   off    = (int*)alloc((size_t)(N + 1) * 4);
    int*   bsum   = (int*)alloc(256 * 4);
    int*   boff   = (int*)alloc(256 * 4);
    int*   csr_src = (int*)alloc((size_t)E * 4);
    int*   gstart  = (int*)alloc((size_t)(G + 1) * 4);
    float* pooled  = (float*)alloc((size_t)G * 128 * 4);

    hipMemsetAsync(cnt, 0, (size_t)N * 4, stream);
    hipMemsetAsync(cursor, 0, (size_t)N * 4, stream);

    const int eb = (E + 255) / 256;
    const int nb = (N + 255) / 256;   // 196 (<=256 required by scan_top)

    hist_dst<<<eb, 256, 0, stream>>>(dst, cnt, E);
    calc_dis<<<nb, 256, 0, stream>>>(cnt, dis, N);
    scan_block<<<nb, 256, 0, stream>>>(cnt, off, bsum, N);
    scan_top<<<1, 256, 0, stream>>>(bsum, boff, off, nb, N);
    scan_add<<<nb, 256, 0, stream>>>(off, boff, N);
    fill_csr<<<eb, 256, 0, stream>>>(src, dst, off, cursor, csr_src, E);

    const int gb = (N + 127) / 128;
    const int ab = (N + 3) / 4;

    gemm128v2<<<gb, 256, 0, stream>>>(x,   W0, dis, hs, N);
    aggregate<<<ab, 256, 0, stream>>>(hs, csr_src, off, dis, b0, act, N, 1);
    gemm128v2<<<gb, 256, 0, stream>>>(act, W1, dis, hs, N);
    aggregate<<<ab, 256, 0, stream>>>(hs, csr_src, off, dis, b1, act, N, 1);
    gemm128v2<<<gb, 256, 0, stream>>>(act, W2, dis, hs, N);
    aggregate<<<ab, 256, 0, stream>>>(hs, csr_src, off, dis, b2, act, N, 0);

    graph_starts<<<(G + 64) / 64, 64, 0, stream>>>(batch, gstart, N, G);
    pool_mean<<<G, 64, 0, stream>>>(act, gstart, pooled, G);
    head_kernel<<<G, 64, 0, stream>>>(pooled, Wout, bout, out, C);
}

// Round 5
// 469.484 us; speedup vs baseline: 2.8450x; 1.2357x over previous
//
#include <hip/hip_runtime.h>
#include <math.h>

// ---------------------------------------------------------------------------
// GCN: 3x (GEMM(+dis scale, bf16 out) -> pull-aggregate -> bias -> tanh)
//      -> mean pool -> head -> log_softmax
// R5: contention-free CSR build via privatized counting sort.
//     N < 65536 -> edge packs into 32 bits ((dst<<16)|src), csr_src is ushort.
//     blk_hist -> scan(38318) -> scatter_packed (private contiguous runs)
//     -> bucket_build (per-bucket count + local scan + fill, L2-resident).
//     No global contended atomics; write amplification ~1.5x instead of 16x.
// ---------------------------------------------------------------------------

#define BLK_EDGES 4096
#define MAXB 128          // max buckets (N<=65536 -> NB<=128)

static __device__ inline unsigned short f2bf(float f) {
    unsigned u = __float_as_uint(f);
    unsigned r = (u + 0x7FFFu + ((u >> 16) & 1u)) >> 16;   // RNE
    return (unsigned short)r;
}

// ---- per-block bucket histogram (bucket = dst >> 9), transposed output ----
__global__ __launch_bounds__(256) void blk_hist(const int* __restrict__ dst,
        int* __restrict__ histT, int E, int NBLK, int NB) {
    __shared__ int h[MAXB];
    int blk = blockIdx.x, t = threadIdx.x;
    for (int i = t; i < NB; i += 256) h[i] = 0;
    __syncthreads();
    int lo = blk * BLK_EDGES;
    int hi = min(E, lo + BLK_EDGES);
    for (int i = lo + t; i < hi; i += 256)
        atomicAdd(&h[dst[i] >> 9], 1);
    __syncthreads();
    for (int i = t; i < NB; i += 256) histT[i * NBLK + blk] = h[i];
}

// ---- 3-kernel exclusive scan (n <= 65536) ---------------------------------
__global__ void scan_block(const int* __restrict__ cnt, int* __restrict__ off,
                           int* __restrict__ bsum, int n) {
    __shared__ int lds[256];
    int t = threadIdx.x;
    int i = blockIdx.x * 256 + t;
    int v = (i < n) ? cnt[i] : 0;
    lds[t] = v;
    __syncthreads();
    for (int d = 1; d < 256; d <<= 1) {
        int add = (t >= d) ? lds[t - d] : 0;
        __syncthreads();
        lds[t] += add;
        __syncthreads();
    }
    if (i < n) off[i] = lds[t] - v;
    if (t == 255) bsum[blockIdx.x] = lds[255];
}

__global__ void scan_top(const int* __restrict__ bsum, int* __restrict__ boff,
                         int* __restrict__ off, int nblocks, int n) {
    __shared__ int lds[256];
    int t = threadIdx.x;
    int v = (t < nblocks) ? bsum[t] : 0;
    lds[t] = v;
    __syncthreads();
    for (int d = 1; d < 256; d <<= 1) {
        int add = (t >= d) ? lds[t - d] : 0;
        __syncthreads();
        lds[t] += add;
        __syncthreads();
    }
    if (t < nblocks) boff[t] = lds[t] - v;
    if (t == 255) off[n] = lds[255];
}

__global__ void scan_add(int* __restrict__ off, const int* __restrict__ boff, int n) {
    int i = blockIdx.x * 256 + threadIdx.x;
    if (i < n) off[i] += boff[blockIdx.x];
}

// ---- scatter packed edges into private (block,bucket) runs ----------------
__global__ __launch_bounds__(256) void scatter_packed(const int* __restrict__ src,
        const int* __restrict__ dst, const int* __restrict__ P,
        unsigned* __restrict__ packed, int E, int NBLK, int NB) {
    __shared__ int cur[MAXB];
    int blk = blockIdx.x, t = threadIdx.x;
    for (int i = t; i < NB; i += 256) cur[i] = P[i * NBLK + blk];
    __syncthreads();
    int lo = blk * BLK_EDGES;
    int hi = min(E, lo + BLK_EDGES);
    for (int i = lo + t; i < hi; i += 256) {
        int d = dst[i];
        int pos = atomicAdd(&cur[d >> 9], 1);   // LDS atomic, block-local
        packed[pos] = ((unsigned)d << 16) | (unsigned)src[i];
    }
}

// ---- per-bucket: node counts, local scan -> off/dis, fill ushort CSR ------
__global__ __launch_bounds__(256) void bucket_build(const unsigned* __restrict__ packed,
        const int* __restrict__ P, int* __restrict__ off, float* __restrict__ dis,
        unsigned short* __restrict__ csr16, int E, int NBLK, int N, int NB) {
    __shared__ int cnt[512];
    __shared__ int loc[512];
    __shared__ int ps[256];
    int b = blockIdx.x, t = threadIdx.x;
    int start = P[b * NBLK];
    int end   = P[(b + 1) * NBLK];   // b==NB-1 -> P[NB*NBLK] == E (scan total)
    cnt[t] = 0; cnt[t + 256] = 0;
    __syncthreads();
    for (int i = start + t; i < end; i += 256)
        atomicAdd(&cnt[(packed[i] >> 16) & 511], 1);
    __syncthreads();
    // exclusive scan of 512 counts (pair-sum + Hillis-Steele on 256)
    int c0 = cnt[2 * t], c1 = cnt[2 * t + 1];
    ps[t] = c0 + c1;
    __syncthreads();
    for (int d = 1; d < 256; d <<= 1) {
        int add = (t >= d) ? ps[t - d] : 0;
        __syncthreads();
        ps[t] += add;
        __syncthreads();
    }
    int pexcl = ps[t] - (c0 + c1);
    loc[2 * t]     = start + pexcl;        // global cursor base
    loc[2 * t + 1] = start + pexcl + c0;
    __syncthreads();
    // write off / dis
    int node0 = b * 512;
    for (int l = t; l < 512; l += 256) {
        int node = node0 + l;
        if (node < N) {
            off[node] = loc[l];
            dis[node] = rsqrtf((float)cnt[l] + 1.0f);
        }
    }
    if (b == NB - 1 && t == 0) off[N] = E;
    __syncthreads();
    // fill (writes stay inside this bucket's contiguous window)
    for (int i = start + t; i < end; i += 256) {
        unsigned p = packed[i];
        int l = (p >> 16) & 511;
        int pos = atomicAdd(&loc[l], 1);
        csr16[pos] = (unsigned short)(p & 0xFFFFu);
    }
}

// ---- GEMM: Hs16[r] = bf16( dis[r] * (A[r] @ W) ),  A: n x 128 -------------
__global__ __launch_bounds__(256, 2) void gemm128v2(const float* __restrict__ A,
        const float* __restrict__ W, const float* __restrict__ dis,
        unsigned short* __restrict__ Hs16, int n) {
    __shared__ float As[64 * 128];   // As[k*128 + r]
    __shared__ float Ws[64 * 128];   // Ws[k*128 + c]
    int t = threadIdx.x;
    int row0 = blockIdx.x * 128;
    int rg = (t & 15) * 8;
    int cg = (t >> 4) * 8;

    float acc[8][8];
#pragma unroll
    for (int i = 0; i < 8; ++i)
#pragma unroll
        for (int j = 0; j < 8; ++j) acc[i][j] = 0.f;

    for (int kk = 0; kk < 128; kk += 64) {
        __syncthreads();
        {
            int r = t & 127;
            int q = t >> 7;
            int grow = row0 + r;
            const float* Ap = A + (size_t)grow * 128 + kk + q * 32;
#pragma unroll
            for (int j = 0; j < 8; ++j) {
                float4 f;
                if (grow < n) f = ((const float4*)Ap)[j];
                else          f = float4{0.f, 0.f, 0.f, 0.f};
                int kb = q * 32 + j * 4;
                As[(kb + 0) * 128 + r] = f.x;
                As[(kb + 1) * 128 + r] = f.y;
                As[(kb + 2) * 128 + r] = f.z;
                As[(kb + 3) * 128 + r] = f.w;
            }
        }
        {
            const float4* Wp = (const float4*)(W + (size_t)kk * 128);
            float4* Wl = (float4*)Ws;
            for (int i = t; i < 64 * 128 / 4; i += 256) Wl[i] = Wp[i];
        }
        __syncthreads();
#pragma unroll 4
        for (int k = 0; k < 64; ++k) {
            float4 a0 = *(const float4*)&As[k * 128 + rg];
            float4 a1 = *(const float4*)&As[k * 128 + rg + 4];
            float4 w0 = *(const float4*)&Ws[k * 128 + cg];
            float4 w1 = *(const float4*)&Ws[k * 128 + cg + 4];
            float a[8] = {a0.x, a0.y, a0.z, a0.w, a1.x, a1.y, a1.z, a1.w};
            float w[8] = {w0.x, w0.y, w0.z, w0.w, w1.x, w1.y, w1.z, w1.w};
#pragma unroll
            for (int i = 0; i < 8; ++i)
#pragma unroll
                for (int j = 0; j < 8; ++j)
                    acc[i][j] = fmaf(a[i], w[j], acc[i][j]);
        }
    }
#pragma unroll
    for (int i = 0; i < 8; ++i) {
        int r = row0 + rg + i;
        if (r < n) {
            float d = dis[r];
            unsigned u0 = (unsigned)f2bf(acc[i][0] * d) | ((unsigned)f2bf(acc[i][1] * d) << 16);
            unsigned u1 = (unsigned)f2bf(acc[i][2] * d) | ((unsigned)f2bf(acc[i][3] * d) << 16);
            unsigned u2 = (unsigned)f2bf(acc[i][4] * d) | ((unsigned)f2bf(acc[i][5] * d) << 16);
            unsigned u3 = (unsigned)f2bf(acc[i][6] * d) | ((unsigned)f2bf(acc[i][7] * d) << 16);
            uint4 o = {u0, u1, u2, u3};
            *(uint4*)(Hs16 + (size_t)r * 128 + cg) = o;
        }
    }
}

// ---- pull aggregation over bf16 table, ushort CSR -------------------------
__global__ __launch_bounds__(256) void aggregate(const unsigned short* __restrict__ hs,
    const unsigned short* __restrict__ csr, const int* __restrict__ off,
    const float* __restrict__ dis, const float* __restrict__ bias,
    float* __restrict__ out, int n, int do_tanh) {
    int node = blockIdx.x * 4 + (threadIdx.x >> 6);
    if (node >= n) return;
    int lane = threadIdx.x & 63;
    int half = lane >> 5;          // edge stream 0/1
    int fq = lane & 31;            // covers features [4*fq, 4*fq+4)
    const uint2* H = (const uint2*)hs;    // 32 uint2 per row

    int e0 = off[node];
    int e1 = off[node + 1];
    int m = e1 - e0;
    int full = m & ~15;
    float ax = 0.f, ay = 0.f, az = 0.f, aw = 0.f;
    for (int i = 0; i < full; i += 16) {
        int base = e0 + i + half;
        int s[8];
#pragma unroll
        for (int j = 0; j < 8; ++j) s[j] = csr[base + 2 * j];
        uint2 v[8];
#pragma unroll
        for (int j = 0; j < 8; ++j) v[j] = H[(size_t)s[j] * 32 + fq];
#pragma unroll
        for (int j = 0; j < 8; ++j) {
            ax += __uint_as_float(v[j].x << 16);
            ay += __uint_as_float(v[j].x & 0xFFFF0000u);
            az += __uint_as_float(v[j].y << 16);
            aw += __uint_as_float(v[j].y & 0xFFFF0000u);
        }
    }
    for (int e = e0 + full + half; e < e1; e += 2) {
        int s = csr[e];
        uint2 v = H[(size_t)s * 32 + fq];
        ax += __uint_as_float(v.x << 16);
        ay += __uint_as_float(v.x & 0xFFFF0000u);
        az += __uint_as_float(v.y << 16);
        aw += __uint_as_float(v.y & 0xFFFF0000u);
    }
    ax += __shfl_xor(ax, 32, 64);
    ay += __shfl_xor(ay, 32, 64);
    az += __shfl_xor(az, 32, 64);
    aw += __shfl_xor(aw, 32, 64);

    uint2 sv = H[(size_t)node * 32 + fq];   // self loop (row pre-scaled by dn)
    ax += __uint_as_float(sv.x << 16);
    ay += __uint_as_float(sv.x & 0xFFFF0000u);
    az += __uint_as_float(sv.y << 16);
    aw += __uint_as_float(sv.y & 0xFFFF0000u);

    float dn = dis[node];
    float4 bv = ((const float4*)bias)[fq];
    float4 o;
    o.x = fmaf(dn, ax, bv.x);
    o.y = fmaf(dn, ay, bv.y);
    o.z = fmaf(dn, az, bv.z);
    o.w = fmaf(dn, aw, bv.w);
    if (do_tanh) {
        o.x = tanhf(o.x); o.y = tanhf(o.y); o.z = tanhf(o.z); o.w = tanhf(o.w);
    }
    if (half == 0)
        *(float4*)(out + (size_t)node * 128 + fq * 4) = o;
}

// ---- per-graph node ranges via binary search on sorted batch --------------
__global__ void graph_starts(const int* __restrict__ batch, int* __restrict__ gstart,
                             int n, int G) {
    int g = blockIdx.x * 64 + threadIdx.x;
    if (g > G) return;
    int lo = 0, hi = n;
    while (lo < hi) {
        int mid = (lo + hi) >> 1;
        if (batch[mid] < g) lo = mid + 1; else hi = mid;
    }
    gstart[g] = lo;
}

__global__ __launch_bounds__(64) void pool_mean(const float* __restrict__ act,
    const int* __restrict__ gstart, float* __restrict__ pooled, int G) {
    int g = blockIdx.x;
    int l = threadIdx.x;
    int lo = gstart[g], hi = gstart[g + 1];
    float accx = 0.f, accy = 0.f;
    for (int i = lo; i < hi; ++i) {
        const float2 v = *(const float2*)(act + (size_t)i * 128 + l * 2);
        accx += v.x;
        accy += v.y;
    }
    int cnt = hi - lo;
    float inv = 1.0f / (float)(cnt > 0 ? cnt : 1);
    pooled[(size_t)g * 128 + 2 * l]     = accx * inv;
    pooled[(size_t)g * 128 + 2 * l + 1] = accy * inv;
}

__global__ __launch_bounds__(64) void head_kernel(const float* __restrict__ pooled,
    const float* __restrict__ Wout, const float* __restrict__ bout,
    float* __restrict__ out, int C) {
    __shared__ float l[16];
    __shared__ float stats[2];
    int g = blockIdx.x;
    int t = threadIdx.x;
    if (t < C) {
        float acc = bout[t];
        for (int f = 0; f < 128; ++f)
            acc = fmaf(pooled[(size_t)g * 128 + f], Wout[(size_t)f * C + t], acc);
        l[t] = acc;
    }
    __syncthreads();
    if (t == 0) {
        float m = -1e30f;
        for (int c = 0; c < C; ++c) m = fmaxf(m, l[c]);
        float s = 0.f;
        for (int c = 0; c < C; ++c) s += expf(l[c] - m);
        stats[0] = m;
        stats[1] = logf(s);
    }
    __syncthreads();
    if (t < C) out[(size_t)g * C + t] = l[t] - stats[0] - stats[1];
}

// ---------------------------------------------------------------------------
extern "C" void kernel_launch(void* const* d_in, const int* in_sizes, int n_in,
                              void* d_out, int out_size, void* d_ws, size_t ws_size,
                              hipStream_t stream) {
    const float* x     = (const float*)d_in[0];
    const int*   edge  = (const int*)d_in[1];
    const int*   batch = (const int*)d_in[2];
    const float* W0 = (const float*)d_in[3];
    const float* b0 = (const float*)d_in[4];
    const float* W1 = (const float*)d_in[5];
    const float* b1 = (const float*)d_in[6];
    const float* W2 = (const float*)d_in[7];
    const float* b2 = (const float*)d_in[8];
    const float* Wout = (const float*)d_in[9];
    const float* bout = (const float*)d_in[10];
    float* out = (float*)d_out;

    const int N = in_sizes[0] / 128;   // 50000 (< 65536 required for packing)
    const int E = in_sizes[1] / 2;     // 1600000
    const int C = in_sizes[10];        // 10
    const int G = out_size / C;        // 512

    const int* src = edge;
    const int* dst = edge + E;

    const int NBLK = (E + BLK_EDGES - 1) / BLK_EDGES;  // 391
    const int NB   = (N + 511) / 512;                  // 98 buckets
    const int NBQ  = NB * NBLK;                        // 38318 scan entries

    char* p = (char*)d_ws;
    auto alloc = [&](size_t bytes) -> void* {
        void* r = (void*)p;
        p += (bytes + 255) & ~(size_t)255;
        return r;
    };
    unsigned short* hs = (unsigned short*)alloc((size_t)N * 128 * 2);  // bf16 table
    float* act    = (float*)alloc((size_t)N * 128 * 4);
    float* dis    = (float*)alloc((size_t)N * 4);
    int*   off    = (int*)alloc((size_t)(N + 1) * 4);
    int*   P      = (int*)alloc((size_t)(NBQ + 1) * 4);   // histT then scanned
    int*   bsum   = (int*)alloc(256 * 4);
    int*   boff   = (int*)alloc(256 * 4);
    unsigned* packed = (unsigned*)alloc((size_t)E * 4);
    unsigned short* csr16 = (unsigned short*)alloc((size_t)E * 2);
    int*   gstart  = (int*)alloc((size_t)(G + 1) * 4);
    float* pooled  = (float*)alloc((size_t)G * 128 * 4);

    const int sb = (NBQ + 255) / 256;   // 150 (<=256 required by scan_top)

    // CSR build (no contended global atomics anywhere)
    blk_hist<<<NBLK, 256, 0, stream>>>(dst, P, E, NBLK, NB);
    scan_block<<<sb, 256, 0, stream>>>(P, P, bsum, NBQ);   // in-place ok (elementwise)
    scan_top<<<1, 256, 0, stream>>>(bsum, boff, P, sb, NBQ);
    scan_add<<<sb, 256, 0, stream>>>(P, boff, NBQ);
    scatter_packed<<<NBLK, 256, 0, stream>>>(src, dst, P, packed, E, NBLK, NB);
    bucket_build<<<NB, 256, 0, stream>>>(packed, P, off, dis, csr16, E, NBLK, N, NB);

    const int gb = (N + 127) / 128;
    const int ab = (N + 3) / 4;

    gemm128v2<<<gb, 256, 0, stream>>>(x,   W0, dis, hs, N);
    aggregate<<<ab, 256, 0, stream>>>(hs, csr16, off, dis, b0, act, N, 1);
    gemm128v2<<<gb, 256, 0, stream>>>(act, W1, dis, hs, N);
    aggregate<<<ab, 256, 0, stream>>>(hs, csr16, off, dis, b1, act, N, 1);
    gemm128v2<<<gb, 256, 0, stream>>>(act, W2, dis, hs, N);
    aggregate<<<ab, 256, 0, stream>>>(hs, csr16, off, dis, b2, act, N, 0);

    graph_starts<<<(G + 64) / 64, 64, 0, stream>>>(batch, gstart, N, G);
    pool_mean<<<G, 64, 0, stream>>>(act, gstart, pooled, G);
    head_kernel<<<G, 64, 0, stream>>>(pooled, Wout, bout, out, C);
}

// Round 6
// 463.607 us; speedup vs baseline: 2.8811x; 1.0127x over previous
//
#include <hip/hip_runtime.h>
#include <math.h>

// ---------------------------------------------------------------------------
// GCN: 3x (GEMM(+dis scale, bf16 out) -> pull-aggregate -> bias -> tanh)
//      -> mean pool -> head -> log_softmax
// R6: aggregate rework for memory-level parallelism:
//     - block stages its 4 nodes' (contiguous) edge indices into LDS, killing
//       the index->gather dependent chain in the hot loop;
//     - explicit double-buffered gather batches (va/vb) force the compiler to
//       keep 16 gathers in flight (R5's VGPR=20 proved it serialized to ~2);
//     - layers 0/1 write bf16 act, GEMMs 1/2 read bf16 (halves that traffic).
// ---------------------------------------------------------------------------

#define BLK_EDGES 4096
#define MAXB 128          // max dst-buckets for CSR build (N<=65536)
#define ECAP 2048         // LDS edge-index capacity per aggregate block

static __device__ inline unsigned short f2bf(float f) {
    unsigned u = __float_as_uint(f);
    unsigned r = (u + 0x7FFFu + ((u >> 16) & 1u)) >> 16;   // RNE
    return (unsigned short)r;
}
static __device__ inline float bf_lo(unsigned u) { return __uint_as_float(u << 16); }
static __device__ inline float bf_hi(unsigned u) { return __uint_as_float(u & 0xFFFF0000u); }

// ---- per-block bucket histogram (bucket = dst >> 9), transposed output ----
__global__ __launch_bounds__(256) void blk_hist(const int* __restrict__ dst,
        int* __restrict__ histT, int E, int NBLK, int NB) {
    __shared__ int h[MAXB];
    int blk = blockIdx.x, t = threadIdx.x;
    for (int i = t; i < NB; i += 256) h[i] = 0;
    __syncthreads();
    int lo = blk * BLK_EDGES;
    int hi = min(E, lo + BLK_EDGES);
    for (int i = lo + t; i < hi; i += 256)
        atomicAdd(&h[dst[i] >> 9], 1);
    __syncthreads();
    for (int i = t; i < NB; i += 256) histT[i * NBLK + blk] = h[i];
}

// ---- 3-kernel exclusive scan (n <= 65536) ---------------------------------
__global__ void scan_block(const int* __restrict__ cnt, int* __restrict__ off,
                           int* __restrict__ bsum, int n) {
    __shared__ int lds[256];
    int t = threadIdx.x;
    int i = blockIdx.x * 256 + t;
    int v = (i < n) ? cnt[i] : 0;
    lds[t] = v;
    __syncthreads();
    for (int d = 1; d < 256; d <<= 1) {
        int add = (t >= d) ? lds[t - d] : 0;
        __syncthreads();
        lds[t] += add;
        __syncthreads();
    }
    if (i < n) off[i] = lds[t] - v;
    if (t == 255) bsum[blockIdx.x] = lds[255];
}

__global__ void scan_top(const int* __restrict__ bsum, int* __restrict__ boff,
                         int* __restrict__ off, int nblocks, int n) {
    __shared__ int lds[256];
    int t = threadIdx.x;
    int v = (t < nblocks) ? bsum[t] : 0;
    lds[t] = v;
    __syncthreads();
    for (int d = 1; d < 256; d <<= 1) {
        int add = (t >= d) ? lds[t - d] : 0;
        __syncthreads();
        lds[t] += add;
        __syncthreads();
    }
    if (t < nblocks) boff[t] = lds[t] - v;
    if (t == 255) off[n] = lds[255];
}

__global__ void scan_add(int* __restrict__ off, const int* __restrict__ boff, int n) {
    int i = blockIdx.x * 256 + threadIdx.x;
    if (i < n) off[i] += boff[blockIdx.x];
}

// ---- scatter packed edges into private (block,bucket) runs ----------------
__global__ __launch_bounds__(256) void scatter_packed(const int* __restrict__ src,
        const int* __restrict__ dst, const int* __restrict__ P,
        unsigned* __restrict__ packed, int E, int NBLK, int NB) {
    __shared__ int cur[MAXB];
    int blk = blockIdx.x, t = threadIdx.x;
    for (int i = t; i < NB; i += 256) cur[i] = P[i * NBLK + blk];
    __syncthreads();
    int lo = blk * BLK_EDGES;
    int hi = min(E, lo + BLK_EDGES);
    for (int i = lo + t; i < hi; i += 256) {
        int d = dst[i];
        int pos = atomicAdd(&cur[d >> 9], 1);   // LDS atomic, block-local
        packed[pos] = ((unsigned)d << 16) | (unsigned)src[i];
    }
}

// ---- per-bucket: node counts, local scan -> off/dis, fill ushort CSR ------
__global__ __launch_bounds__(256) void bucket_build(const unsigned* __restrict__ packed,
        const int* __restrict__ P, int* __restrict__ off, float* __restrict__ dis,
        unsigned short* __restrict__ csr16, int E, int NBLK, int N, int NB) {
    __shared__ int cnt[512];
    __shared__ int loc[512];
    __shared__ int ps[256];
    int b = blockIdx.x, t = threadIdx.x;
    int start = P[b * NBLK];
    int end   = P[(b + 1) * NBLK];
    cnt[t] = 0; cnt[t + 256] = 0;
    __syncthreads();
    for (int i = start + t; i < end; i += 256)
        atomicAdd(&cnt[(packed[i] >> 16) & 511], 1);
    __syncthreads();
    int c0 = cnt[2 * t], c1 = cnt[2 * t + 1];
    ps[t] = c0 + c1;
    __syncthreads();
    for (int d = 1; d < 256; d <<= 1) {
        int add = (t >= d) ? ps[t - d] : 0;
        __syncthreads();
        ps[t] += add;
        __syncthreads();
    }
    int pexcl = ps[t] - (c0 + c1);
    loc[2 * t]     = start + pexcl;
    loc[2 * t + 1] = start + pexcl + c0;
    __syncthreads();
    int node0 = b * 512;
    for (int l = t; l < 512; l += 256) {
        int node = node0 + l;
        if (node < N) {
            off[node] = loc[l];
            dis[node] = rsqrtf((float)cnt[l] + 1.0f);
        }
    }
    if (b == NB - 1 && t == 0) off[N] = E;
    __syncthreads();
    for (int i = start + t; i < end; i += 256) {
        unsigned p = packed[i];
        int l = (p >> 16) & 511;
        int pos = atomicAdd(&loc[l], 1);
        csr16[pos] = (unsigned short)(p & 0xFFFFu);
    }
}

// ---- GEMM: Hs16[r] = bf16( dis[r] * (A[r] @ W) ), A fp32 or bf16 ----------
template<int IN_BF16>
__global__ __launch_bounds__(256, 2) void gemm128v3(const void* __restrict__ Av,
        const float* __restrict__ W, const float* __restrict__ dis,
        unsigned short* __restrict__ Hs16, int n) {
    __shared__ float As[64 * 128];   // As[k*128 + r]
    __shared__ float Ws[64 * 128];   // Ws[k*128 + c]
    int t = threadIdx.x;
    int row0 = blockIdx.x * 128;
    int rg = (t & 15) * 8;
    int cg = (t >> 4) * 8;

    float acc[8][8];
#pragma unroll
    for (int i = 0; i < 8; ++i)
#pragma unroll
        for (int j = 0; j < 8; ++j) acc[i][j] = 0.f;

    for (int kk = 0; kk < 128; kk += 64) {
        __syncthreads();
        {
            int r = t & 127;
            int q = t >> 7;          // covers k range [kk+q*32, kk+q*32+32)
            int grow = row0 + r;
            if (IN_BF16) {
                const unsigned short* Ap = (const unsigned short*)Av
                                           + (size_t)grow * 128 + kk + q * 32;
#pragma unroll
                for (int j = 0; j < 4; ++j) {
                    uint4 u;
                    if (grow < n) u = ((const uint4*)Ap)[j];
                    else          u = uint4{0u, 0u, 0u, 0u};
                    int kb = q * 32 + j * 8;
                    As[(kb + 0) * 128 + r] = bf_lo(u.x);
                    As[(kb + 1) * 128 + r] = bf_hi(u.x);
                    As[(kb + 2) * 128 + r] = bf_lo(u.y);
                    As[(kb + 3) * 128 + r] = bf_hi(u.y);
                    As[(kb + 4) * 128 + r] = bf_lo(u.z);
                    As[(kb + 5) * 128 + r] = bf_hi(u.z);
                    As[(kb + 6) * 128 + r] = bf_lo(u.w);
                    As[(kb + 7) * 128 + r] = bf_hi(u.w);
                }
            } else {
                const float* Ap = (const float*)Av + (size_t)grow * 128 + kk + q * 32;
#pragma unroll
                for (int j = 0; j < 8; ++j) {
                    float4 f;
                    if (grow < n) f = ((const float4*)Ap)[j];
                    else          f = float4{0.f, 0.f, 0.f, 0.f};
                    int kb = q * 32 + j * 4;
                    As[(kb + 0) * 128 + r] = f.x;
                    As[(kb + 1) * 128 + r] = f.y;
                    As[(kb + 2) * 128 + r] = f.z;
                    As[(kb + 3) * 128 + r] = f.w;
                }
            }
        }
        {
            const float4* Wp = (const float4*)(W + (size_t)kk * 128);
            float4* Wl = (float4*)Ws;
            for (int i = t; i < 64 * 128 / 4; i += 256) Wl[i] = Wp[i];
        }
        __syncthreads();
#pragma unroll 4
        for (int k = 0; k < 64; ++k) {
            float4 a0 = *(const float4*)&As[k * 128 + rg];
            float4 a1 = *(const float4*)&As[k * 128 + rg + 4];
            float4 w0 = *(const float4*)&Ws[k * 128 + cg];
            float4 w1 = *(const float4*)&Ws[k * 128 + cg + 4];
            float a[8] = {a0.x, a0.y, a0.z, a0.w, a1.x, a1.y, a1.z, a1.w};
            float w[8] = {w0.x, w0.y, w0.z, w0.w, w1.x, w1.y, w1.z, w1.w};
#pragma unroll
            for (int i = 0; i < 8; ++i)
#pragma unroll
                for (int j = 0; j < 8; ++j)
                    acc[i][j] = fmaf(a[i], w[j], acc[i][j]);
        }
    }
#pragma unroll
    for (int i = 0; i < 8; ++i) {
        int r = row0 + rg + i;
        if (r < n) {
            float d = dis[r];
            unsigned u0 = (unsigned)f2bf(acc[i][0] * d) | ((unsigned)f2bf(acc[i][1] * d) << 16);
            unsigned u1 = (unsigned)f2bf(acc[i][2] * d) | ((unsigned)f2bf(acc[i][3] * d) << 16);
            unsigned u2 = (unsigned)f2bf(acc[i][4] * d) | ((unsigned)f2bf(acc[i][5] * d) << 16);
            unsigned u3 = (unsigned)f2bf(acc[i][6] * d) | ((unsigned)f2bf(acc[i][7] * d) << 16);
            uint4 o = {u0, u1, u2, u3};
            *(uint4*)(Hs16 + (size_t)r * 128 + cg) = o;
        }
    }
}

// ---- pull aggregation: LDS-staged indices + double-buffered gathers -------
// 4 nodes/block (contiguous CSR ranges -> one cooperative index stage).
// Per wave: 2 half-wave edge streams, batches of 16 edges (8/stream),
// double-buffered so ~16 gathers stay in flight.
template<int DO_TANH, int OUT_BF16>
__global__ __launch_bounds__(256) void aggregate3(const unsigned short* __restrict__ hs,
    const unsigned short* __restrict__ csr, const int* __restrict__ off,
    const float* __restrict__ dis, const float* __restrict__ bias,
    void* __restrict__ outp, int n) {
    __shared__ unsigned short eidx[ECAP];
    int t = threadIdx.x;
    int node0 = blockIdx.x * 4;
    int b0 = off[node0];
    int top = node0 + 4 < n ? node0 + 4 : n;
    int b4 = off[top];
    int mblk = b4 - b0;
    bool staged = (mblk <= ECAP);
    if (staged)
        for (int i = t; i < mblk; i += 256) eidx[i] = csr[b0 + i];
    __syncthreads();

    int node = node0 + (t >> 6);
    if (node >= n) return;
    int lane = t & 63;
    int half = lane >> 5;
    int fq = lane & 31;
    const uint2* H = (const uint2*)hs;

    int e0 = off[node];
    int e1 = off[node + 1];
    int le0 = e0 - b0;
    int m = e1 - e0;
    float ax = 0.f, ay = 0.f, az = 0.f, aw = 0.f;

    uint2 va[8], vb[8];
    auto sumB = [&](uint2* v) {
#pragma unroll
        for (int j = 0; j < 8; ++j) {
            ax += bf_lo(v[j].x); ay += bf_hi(v[j].x);
            az += bf_lo(v[j].y); aw += bf_hi(v[j].y);
        }
    };
    auto loadL = [&](int i, uint2* v) {
        int s[8];
#pragma unroll
        for (int j = 0; j < 8; ++j) s[j] = eidx[le0 + i + half + 2 * j];
#pragma unroll
        for (int j = 0; j < 8; ++j) v[j] = H[(size_t)s[j] * 32 + fq];
    };
    auto loadG = [&](int i, uint2* v) {
        int s[8];
#pragma unroll
        for (int j = 0; j < 8; ++j) s[j] = csr[e0 + i + half + 2 * j];
#pragma unroll
        for (int j = 0; j < 8; ++j) v[j] = H[(size_t)s[j] * 32 + fq];
    };

    int nfull = m & ~15;
    if (staged) {
        if (nfull) {
            int B = nfull >> 4;
            loadL(0, va);
            int k = 1;
            for (; k + 1 < B; k += 2) {
                loadL(k << 4, vb);       sumB(va);
                loadL((k + 1) << 4, va); sumB(vb);
            }
            if (k < B) { loadL(k << 4, vb); sumB(va); sumB(vb); }
            else       { sumB(va); }
        }
        for (int e = nfull + half; e < m; e += 2) {
            int s = eidx[le0 + e];
            uint2 v = H[(size_t)s * 32 + fq];
            ax += bf_lo(v.x); ay += bf_hi(v.x);
            az += bf_lo(v.y); aw += bf_hi(v.y);
        }
    } else {
        if (nfull) {
            int B = nfull >> 4;
            loadG(0, va);
            int k = 1;
            for (; k + 1 < B; k += 2) {
                loadG(k << 4, vb);       sumB(va);
                loadG((k + 1) << 4, va); sumB(vb);
            }
            if (k < B) { loadG(k << 4, vb); sumB(va); sumB(vb); }
            else       { sumB(va); }
        }
        for (int e = nfull + half; e < m; e += 2) {
            int s = csr[e0 + e];
            uint2 v = H[(size_t)s * 32 + fq];
            ax += bf_lo(v.x); ay += bf_hi(v.x);
            az += bf_lo(v.y); aw += bf_hi(v.y);
        }
    }

    // combine half-wave streams (lane l and l^32 share fq)
    ax += __shfl_xor(ax, 32, 64);
    ay += __shfl_xor(ay, 32, 64);
    az += __shfl_xor(az, 32, 64);
    aw += __shfl_xor(aw, 32, 64);

    uint2 sv = H[(size_t)node * 32 + fq];   // self loop (row pre-scaled by dn)
    ax += bf_lo(sv.x); ay += bf_hi(sv.x);
    az += bf_lo(sv.y); aw += bf_hi(sv.y);

    float dn = dis[node];
    float4 bv = ((const float4*)bias)[fq];
    float ox = fmaf(dn, ax, bv.x);
    float oy = fmaf(dn, ay, bv.y);
    float oz = fmaf(dn, az, bv.z);
    float ow = fmaf(dn, aw, bv.w);
    if (DO_TANH) {
        ox = tanhf(ox); oy = tanhf(oy); oz = tanhf(oz); ow = tanhf(ow);
    }
    if (half == 0) {
        if (OUT_BF16) {
            uint2 o;
            o.x = (unsigned)f2bf(ox) | ((unsigned)f2bf(oy) << 16);
            o.y = (unsigned)f2bf(oz) | ((unsigned)f2bf(ow) << 16);
            ((uint2*)outp)[(size_t)node * 32 + fq] = o;
        } else {
            float4 o = {ox, oy, oz, ow};
            *(float4*)((float*)outp + (size_t)node * 128 + fq * 4) = o;
        }
    }
}

// ---- per-graph node ranges via binary search on sorted batch --------------
__global__ void graph_starts(const int* __restrict__ batch, int* __restrict__ gstart,
                             int n, int G) {
    int g = blockIdx.x * 64 + threadIdx.x;
    if (g > G) return;
    int lo = 0, hi = n;
    while (lo < hi) {
        int mid = (lo + hi) >> 1;
        if (batch[mid] < g) lo = mid + 1; else hi = mid;
    }
    gstart[g] = lo;
}

__global__ __launch_bounds__(64) void pool_mean(const float* __restrict__ act,
    const int* __restrict__ gstart, float* __restrict__ pooled, int G) {
    int g = blockIdx.x;
    int l = threadIdx.x;
    int lo = gstart[g], hi = gstart[g + 1];
    float accx = 0.f, accy = 0.f;
    for (int i = lo; i < hi; ++i) {
        const float2 v = *(const float2*)(act + (size_t)i * 128 + l * 2);
        accx += v.x;
        accy += v.y;
    }
    int cnt = hi - lo;
    float inv = 1.0f / (float)(cnt > 0 ? cnt : 1);
    pooled[(size_t)g * 128 + 2 * l]     = accx * inv;
    pooled[(size_t)g * 128 + 2 * l + 1] = accy * inv;
}

__global__ __launch_bounds__(64) void head_kernel(const float* __restrict__ pooled,
    const float* __restrict__ Wout, const float* __restrict__ bout,
    float* __restrict__ out, int C) {
    __shared__ float l[16];
    __shared__ float stats[2];
    int g = blockIdx.x;
    int t = threadIdx.x;
    if (t < C) {
        float acc = bout[t];
        for (int f = 0; f < 128; ++f)
            acc = fmaf(pooled[(size_t)g * 128 + f], Wout[(size_t)f * C + t], acc);
        l[t] = acc;
    }
    __syncthreads();
    if (t == 0) {
        float m = -1e30f;
        for (int c = 0; c < C; ++c) m = fmaxf(m, l[c]);
        float s = 0.f;
        for (int c = 0; c < C; ++c) s += expf(l[c] - m);
        stats[0] = m;
        stats[1] = logf(s);
    }
    __syncthreads();
    if (t < C) out[(size_t)g * C + t] = l[t] - stats[0] - stats[1];
}

// ---------------------------------------------------------------------------
extern "C" void kernel_launch(void* const* d_in, const int* in_sizes, int n_in,
                              void* d_out, int out_size, void* d_ws, size_t ws_size,
                              hipStream_t stream) {
    const float* x     = (const float*)d_in[0];
    const int*   edge  = (const int*)d_in[1];
    const int*   batch = (const int*)d_in[2];
    const float* W0 = (const float*)d_in[3];
    const float* b0 = (const float*)d_in[4];
    const float* W1 = (const float*)d_in[5];
    const float* b1 = (const float*)d_in[6];
    const float* W2 = (const float*)d_in[7];
    const float* b2 = (const float*)d_in[8];
    const float* Wout = (const float*)d_in[9];
    const float* bout = (const float*)d_in[10];
    float* out = (float*)d_out;

    const int N = in_sizes[0] / 128;   // 50000 (< 65536 required for packing)
    const int E = in_sizes[1] / 2;     // 1600000
    const int C = in_sizes[10];        // 10
    const int G = out_size / C;        // 512

    const int* src = edge;
    const int* dst = edge + E;

    const int NBLK = (E + BLK_EDGES - 1) / BLK_EDGES;  // 391
    const int NB   = (N + 511) / 512;                  // 98 buckets
    const int NBQ  = NB * NBLK;                        // 38318 scan entries

    char* p = (char*)d_ws;
    auto alloc = [&](size_t bytes) -> void* {
        void* r = (void*)p;
        p += (bytes + 255) & ~(size_t)255;
        return r;
    };
    unsigned short* hs = (unsigned short*)alloc((size_t)N * 128 * 2);  // bf16 table
    float* act    = (float*)alloc((size_t)N * 128 * 4);  // bf16 (L0/1) or fp32 (L2)
    float* dis    = (float*)alloc((size_t)N * 4);
    int*   off    = (int*)alloc((size_t)(N + 1) * 4);
    int*   P      = (int*)alloc((size_t)(NBQ + 1) * 4);
    int*   bsum   = (int*)alloc(256 * 4);
    int*   boff   = (int*)alloc(256 * 4);
    unsigned* packed = (unsigned*)alloc((size_t)E * 4);
    unsigned short* csr16 = (unsigned short*)alloc((size_t)E * 2);
    int*   gstart  = (int*)alloc((size_t)(G + 1) * 4);
    float* pooled  = (float*)alloc((size_t)G * 128 * 4);

    const int sb = (NBQ + 255) / 256;   // 150 (<=256 required by scan_top)

    // CSR build (no contended global atomics anywhere)
    blk_hist<<<NBLK, 256, 0, stream>>>(dst, P, E, NBLK, NB);
    scan_block<<<sb, 256, 0, stream>>>(P, P, bsum, NBQ);
    scan_top<<<1, 256, 0, stream>>>(bsum, boff, P, sb, NBQ);
    scan_add<<<sb, 256, 0, stream>>>(P, boff, NBQ);
    scatter_packed<<<NBLK, 256, 0, stream>>>(src, dst, P, packed, E, NBLK, NB);
    bucket_build<<<NB, 256, 0, stream>>>(packed, P, off, dis, csr16, E, NBLK, N, NB);

    const int gb = (N + 127) / 128;
    const int ab = (N + 3) / 4;

    gemm128v3<0><<<gb, 256, 0, stream>>>(x,   W0, dis, hs, N);
    aggregate3<1, 1><<<ab, 256, 0, stream>>>(hs, csr16, off, dis, b0, act, N);
    gemm128v3<1><<<gb, 256, 0, stream>>>(act, W1, dis, hs, N);
    aggregate3<1, 1><<<ab, 256, 0, stream>>>(hs, csr16, off, dis, b1, act, N);
    gemm128v3<1><<<gb, 256, 0, stream>>>(act, W2, dis, hs, N);
    aggregate3<0, 0><<<ab, 256, 0, stream>>>(hs, csr16, off, dis, b2, act, N);

    graph_starts<<<(G + 64) / 64, 64, 0, stream>>>(batch, gstart, N, G);
    pool_mean<<<G, 64, 0, stream>>>(act, gstart, pooled, G);
    head_kernel<<<G, 64, 0, stream>>>(pooled, Wout, bout, out, C);
}